// Round 1
// baseline (2591.453 us; speedup 1.0000x reference)
//
#include <hip/hip_runtime.h>

#define NUM_USERS   100000
#define NUM_BUNDLES 50000
#define N_NODES     150000
#define EMB         64
#define NNZ         3000000
#define BATCH       2048
#define NUM_CAND    100
#define EMBED_L2_NORM 0.0001f

// ws layout: [0, N_NODES*EMB) floats = embed_1 accumulator, then all_embeds (in-place)
//            [N_NODES*EMB] = loss accumulator (sum of squares, pre-scale)
#define ACC_FLOATS ((size_t)N_NODES * EMB)

// ---------------------------------------------------------------------------
// K2: scatter-add  acc[row] += val * embed_0[col]   (16 lanes per edge, float4)
// ---------------------------------------------------------------------------
__global__ void scatter_kernel(const float* __restrict__ users_feat,
                               const float* __restrict__ bundles_feat,
                               const float* __restrict__ vals,
                               const int*   __restrict__ rows,
                               const int*   __restrict__ cols,
                               float*       __restrict__ acc) {
    long long tid = (long long)blockIdx.x * blockDim.x + threadIdx.x;
    int e    = (int)(tid >> 4);
    int lane = (int)(tid & 15);
    if (e >= NNZ) return;
    int   row = rows[e];
    int   col = cols[e];
    float v   = vals[e];
    const float4* src = (col < NUM_USERS)
        ? (const float4*)(users_feat   + (size_t)col * EMB)
        : (const float4*)(bundles_feat + (size_t)(col - NUM_USERS) * EMB);
    float4 x = src[lane];
    float* dst = acc + (size_t)row * EMB + lane * 4;
    atomicAdd(dst + 0, v * x.x);
    atomicAdd(dst + 1, v * x.y);
    atomicAdd(dst + 2, v * x.z);
    atomicAdd(dst + 3, v * x.w);
}

// ---------------------------------------------------------------------------
// K3: all_embeds = 0.5*embed_0 + 0.5*acc  (in place over acc) + sum-of-squares
// ---------------------------------------------------------------------------
__global__ void combine_kernel(const float* __restrict__ users_feat,
                               const float* __restrict__ bundles_feat,
                               float*       __restrict__ acc,
                               float*       __restrict__ loss_acc) {
    const int TOTAL4 = N_NODES * (EMB / 4);        // 2.4M float4
    const int U4     = NUM_USERS * (EMB / 4);
    float lsum = 0.f;
    for (int i = blockIdx.x * blockDim.x + threadIdx.x; i < TOTAL4;
         i += gridDim.x * blockDim.x) {
        float4 a = (i < U4) ? ((const float4*)users_feat)[i]
                            : ((const float4*)bundles_feat)[i - U4];
        float4* pa = (float4*)acc + i;
        float4 b = *pa;
        float4 r;
        r.x = 0.5f * (a.x + b.x);
        r.y = 0.5f * (a.y + b.y);
        r.z = 0.5f * (a.z + b.z);
        r.w = 0.5f * (a.w + b.w);
        *pa = r;
        lsum += r.x * r.x + r.y * r.y + r.z * r.z + r.w * r.w;
    }
    // wave reduce (64 lanes)
    for (int off = 32; off > 0; off >>= 1) lsum += __shfl_down(lsum, off);
    __shared__ float ws_[4];
    int wid = threadIdx.x >> 6;
    if ((threadIdx.x & 63) == 0) ws_[wid] = lsum;
    __syncthreads();
    if (threadIdx.x == 0) {
        float s = ws_[0] + ws_[1] + ws_[2] + ws_[3];
        atomicAdd(loss_acc, s);
    }
}

// ---------------------------------------------------------------------------
// K4: pred[b,c] = dot(uf[users[b]], bf[bundles[b,c]])   (16 lanes per pair)
// ---------------------------------------------------------------------------
__global__ void pred_kernel(const float* __restrict__ acc,
                            const int*   __restrict__ users,
                            const int*   __restrict__ bundles,
                            float*       __restrict__ out) {
    long long tid = (long long)blockIdx.x * blockDim.x + threadIdx.x;
    int pair = (int)(tid >> 4);
    int lane = (int)(tid & 15);
    if (pair >= BATCH * NUM_CAND) return;
    int b  = pair / NUM_CAND;
    int u  = users[b];            // users is [BATCH,1]
    int bd = bundles[pair];       // bundles flat [BATCH*NUM_CAND]
    float4 uu = ((const float4*)(acc + (size_t)u * EMB))[lane];
    float4 bb = ((const float4*)(acc + (size_t)(NUM_USERS + bd) * EMB))[lane];
    float d = uu.x * bb.x + uu.y * bb.y + uu.z * bb.z + uu.w * bb.w;
    d += __shfl_xor(d, 8, 16);
    d += __shfl_xor(d, 4, 16);
    d += __shfl_xor(d, 2, 16);
    d += __shfl_xor(d, 1, 16);
    if (lane == 0) out[pair] = d;
}

// ---------------------------------------------------------------------------
// K5: user_score_bound[b] = dot(uf[users[b]], user_bound) ; thread 0 writes loss
// ---------------------------------------------------------------------------
__global__ void usb_kernel(const float* __restrict__ acc,
                           const int*   __restrict__ users,
                           const float* __restrict__ user_bound,
                           const float* __restrict__ loss_acc,
                           float*       __restrict__ out) {
    long long tid = (long long)blockIdx.x * blockDim.x + threadIdx.x;
    int b    = (int)(tid >> 4);
    int lane = (int)(tid & 15);
    if (b >= BATCH) return;
    int u = users[b];
    float4 uu = ((const float4*)(acc + (size_t)u * EMB))[lane];
    float4 w  = ((const float4*)user_bound)[lane];
    float d = uu.x * w.x + uu.y * w.y + uu.z * w.z + uu.w * w.w;
    d += __shfl_xor(d, 8, 16);
    d += __shfl_xor(d, 4, 16);
    d += __shfl_xor(d, 2, 16);
    d += __shfl_xor(d, 1, 16);
    if (lane == 0) out[BATCH * NUM_CAND + b] = d;
    if (tid == 0)  out[BATCH * NUM_CAND + BATCH] = EMBED_L2_NORM * loss_acc[0];
}

extern "C" void kernel_launch(void* const* d_in, const int* in_sizes, int n_in,
                              void* d_out, int out_size, void* d_ws, size_t ws_size,
                              hipStream_t stream) {
    const float* users_feat   = (const float*)d_in[0];
    const float* bundles_feat = (const float*)d_in[1];
    const float* user_bound   = (const float*)d_in[2];
    const float* graph_vals   = (const float*)d_in[3];
    const int*   graph_rows   = (const int*)d_in[4];
    const int*   graph_cols   = (const int*)d_in[5];
    const int*   users        = (const int*)d_in[6];
    const int*   bundles      = (const int*)d_in[7];
    float* out = (float*)d_out;

    float* acc      = (float*)d_ws;
    float* loss_acc = acc + ACC_FLOATS;

    // zero accumulator + loss slot
    hipMemsetAsync(d_ws, 0, (ACC_FLOATS + 1) * sizeof(float), stream);

    // scatter: NNZ edges * 16 lanes
    {
        long long threads = (long long)NNZ * 16;
        int block = 256;
        int grid  = (int)((threads + block - 1) / block);
        scatter_kernel<<<grid, block, 0, stream>>>(users_feat, bundles_feat,
                                                   graph_vals, graph_rows,
                                                   graph_cols, acc);
    }

    // combine + loss
    combine_kernel<<<2048, 256, 0, stream>>>(users_feat, bundles_feat, acc, loss_acc);

    // pred
    {
        long long threads = (long long)BATCH * NUM_CAND * 16;
        int block = 256;
        int grid  = (int)((threads + block - 1) / block);
        pred_kernel<<<grid, block, 0, stream>>>(acc, users, bundles, out);
    }

    // user_score_bound + loss write
    {
        long long threads = (long long)BATCH * 16;
        int block = 256;
        int grid  = (int)((threads + block - 1) / block);
        usb_kernel<<<grid, block, 0, stream>>>(acc, users, user_bound, loss_acc, out);
    }
}

// Round 2
// 928.698 us; speedup vs baseline: 2.7904x; 2.7904x over previous
//
#include <hip/hip_runtime.h>

#define NUM_USERS   100000
#define NUM_BUNDLES 50000
#define N_NODES     150000
#define EMB         64
#define NNZ         3000000
#define BATCH       2048
#define NUM_CAND    100
#define EMBED_L2_NORM 0.0001f

// ---------------------------------------------------------------------------
// ws layout (sorted path):
//   float allemb[N_NODES*EMB]      9,600,000 f32   (38.4 MB)
//   int   hist[N_NODES]              150,000
//   float loss[1]                          1       (memset together with hist)
//   int   offsets[N_NODES+1]         150,001
//   int   cursor[N_NODES]            150,000
//   int2  sorted[NNZ]              3,000,000 int2  (24 MB, 8B-aligned)
// ---------------------------------------------------------------------------
#define ALLEMB_FLOATS ((size_t)N_NODES * EMB)
#define WS_NEEDED_BYTES ((ALLEMB_FLOATS + 150000 + 1 + 150001 + 150000) * 4 + (size_t)NNZ * 8)

// ============================ sorted path ==================================

__global__ void hist_kernel(const int* __restrict__ rows, int* __restrict__ hist) {
    int e = blockIdx.x * blockDim.x + threadIdx.x;
    if (e >= NNZ) return;
    atomicAdd(&hist[rows[e]], 1);
}

// single-block scan: 1024 threads, 4 elems/thread, 37 chunks
__global__ void scan_kernel(const int* __restrict__ hist,
                            int* __restrict__ offsets,
                            int* __restrict__ cursor) {
    __shared__ int wave_tot[16];
    __shared__ int wave_pref[16];
    __shared__ int s_chunk_total;
    __shared__ int s_carry;
    if (threadIdx.x == 0) s_carry = 0;
    __syncthreads();
    const int lane = threadIdx.x & 63;
    const int wid  = threadIdx.x >> 6;
    for (int base = 0; base < N_NODES; base += 1024 * 4) {
        int idx = base + threadIdx.x * 4;
        int v0 = 0, v1 = 0, v2 = 0, v3 = 0;
        if (idx + 3 < N_NODES) {
            int4 h = *(const int4*)(hist + idx);
            v0 = h.x; v1 = h.y; v2 = h.z; v3 = h.w;
        } else {
            if (idx + 0 < N_NODES) v0 = hist[idx + 0];
            if (idx + 1 < N_NODES) v1 = hist[idx + 1];
            if (idx + 2 < N_NODES) v2 = hist[idx + 2];
        }
        int tsum = v0 + v1 + v2 + v3;
        // inclusive 64-lane scan of tsum
        int x = tsum;
        #pragma unroll
        for (int off = 1; off < 64; off <<= 1) {
            int t = __shfl_up(x, off);
            if (lane >= off) x += t;
        }
        if (lane == 63) wave_tot[wid] = x;
        __syncthreads();
        if (wid == 0 && lane < 16) {
            int w = wave_tot[lane];
            int y = w;
            #pragma unroll
            for (int off = 1; off < 16; off <<= 1) {
                int t = __shfl_up(y, off);
                if (lane >= off) y += t;
            }
            wave_pref[lane] = y - w;          // exclusive
            if (lane == 15) s_chunk_total = y; // inclusive total of chunk
        }
        __syncthreads();
        int excl = s_carry + wave_pref[wid] + (x - tsum);
        if (idx < N_NODES)     { offsets[idx]     = excl; cursor[idx]     = excl; }
        excl += v0;
        if (idx + 1 < N_NODES) { offsets[idx + 1] = excl; cursor[idx + 1] = excl; }
        excl += v1;
        if (idx + 2 < N_NODES) { offsets[idx + 2] = excl; cursor[idx + 2] = excl; }
        excl += v2;
        if (idx + 3 < N_NODES) { offsets[idx + 3] = excl; cursor[idx + 3] = excl; }
        __syncthreads();
        if (threadIdx.x == 0) s_carry += s_chunk_total;
        __syncthreads();
    }
    if (threadIdx.x == 0) offsets[N_NODES] = s_carry;   // == NNZ
}

__global__ void place_kernel(const float* __restrict__ vals,
                             const int*   __restrict__ rows,
                             const int*   __restrict__ cols,
                             int* __restrict__ cursor,
                             int2* __restrict__ sorted) {
    int e = blockIdx.x * blockDim.x + threadIdx.x;
    if (e >= NNZ) return;
    int row = rows[e];
    int pos = atomicAdd(&cursor[row], 1);
    int2 p;
    p.x = __float_as_int(vals[e]);
    p.y = cols[e];
    sorted[pos] = p;
}

// 16 lanes per row: register-accumulate edges, fuse 0.5*e0+0.5*e1 + loss
__global__ void gather_kernel(const float* __restrict__ users_feat,
                              const float* __restrict__ bundles_feat,
                              const int*   __restrict__ offsets,
                              const int2*  __restrict__ sorted,
                              float* __restrict__ allemb,
                              float* __restrict__ loss_acc) {
    int tid  = blockIdx.x * blockDim.x + threadIdx.x;
    int row  = tid >> 4;
    int lane = tid & 15;
    bool valid = row < N_NODES;
    float4 acc = {0.f, 0.f, 0.f, 0.f};
    if (valid) {
        int beg = offsets[row], end = offsets[row + 1];
        for (int e = beg; e < end; ++e) {
            int2 p = sorted[e];
            float v = __int_as_float(p.x);
            int col = p.y;
            const float4* src = (col < NUM_USERS)
                ? (const float4*)(users_feat   + (size_t)col * EMB)
                : (const float4*)(bundles_feat + (size_t)(col - NUM_USERS) * EMB);
            float4 x = src[lane];
            acc.x += v * x.x; acc.y += v * x.y; acc.z += v * x.z; acc.w += v * x.w;
        }
        float4 e0 = (row < NUM_USERS)
            ? ((const float4*)(users_feat   + (size_t)row * EMB))[lane]
            : ((const float4*)(bundles_feat + (size_t)(row - NUM_USERS) * EMB))[lane];
        acc.x = 0.5f * (e0.x + acc.x);
        acc.y = 0.5f * (e0.y + acc.y);
        acc.z = 0.5f * (e0.z + acc.z);
        acc.w = 0.5f * (e0.w + acc.w);
        ((float4*)(allemb + (size_t)row * EMB))[lane] = acc;
    }
    // loss: sum of squares across whole wave (rows differ per 16-lane group; all go to same sum)
    float sq = valid ? (acc.x * acc.x + acc.y * acc.y + acc.z * acc.z + acc.w * acc.w) : 0.f;
    #pragma unroll
    for (int off = 32; off > 0; off >>= 1) sq += __shfl_xor(sq, off);
    if ((threadIdx.x & 63) == 0) atomicAdd(loss_acc, sq);
}

// ============================ fallback path =================================

__global__ void scatter_kernel(const float* __restrict__ users_feat,
                               const float* __restrict__ bundles_feat,
                               const float* __restrict__ vals,
                               const int*   __restrict__ rows,
                               const int*   __restrict__ cols,
                               float*       __restrict__ acc) {
    long long tid = (long long)blockIdx.x * blockDim.x + threadIdx.x;
    int e    = (int)(tid >> 4);
    int lane = (int)(tid & 15);
    if (e >= NNZ) return;
    int   row = rows[e];
    int   col = cols[e];
    float v   = vals[e];
    const float4* src = (col < NUM_USERS)
        ? (const float4*)(users_feat   + (size_t)col * EMB)
        : (const float4*)(bundles_feat + (size_t)(col - NUM_USERS) * EMB);
    float4 x = src[lane];
    float* dst = acc + (size_t)row * EMB + lane * 4;
    atomicAdd(dst + 0, v * x.x);
    atomicAdd(dst + 1, v * x.y);
    atomicAdd(dst + 2, v * x.z);
    atomicAdd(dst + 3, v * x.w);
}

__global__ void combine_kernel(const float* __restrict__ users_feat,
                               const float* __restrict__ bundles_feat,
                               float*       __restrict__ acc,
                               float*       __restrict__ loss_acc) {
    const int TOTAL4 = N_NODES * (EMB / 4);
    const int U4     = NUM_USERS * (EMB / 4);
    float lsum = 0.f;
    for (int i = blockIdx.x * blockDim.x + threadIdx.x; i < TOTAL4;
         i += gridDim.x * blockDim.x) {
        float4 a = (i < U4) ? ((const float4*)users_feat)[i]
                            : ((const float4*)bundles_feat)[i - U4];
        float4* pa = (float4*)acc + i;
        float4 b = *pa;
        float4 r;
        r.x = 0.5f * (a.x + b.x);
        r.y = 0.5f * (a.y + b.y);
        r.z = 0.5f * (a.z + b.z);
        r.w = 0.5f * (a.w + b.w);
        *pa = r;
        lsum += r.x * r.x + r.y * r.y + r.z * r.z + r.w * r.w;
    }
    #pragma unroll
    for (int off = 32; off > 0; off >>= 1) lsum += __shfl_down(lsum, off);
    __shared__ float ws_[4];
    int wid = threadIdx.x >> 6;
    if ((threadIdx.x & 63) == 0) ws_[wid] = lsum;
    __syncthreads();
    if (threadIdx.x == 0) atomicAdd(loss_acc, ws_[0] + ws_[1] + ws_[2] + ws_[3]);
}

// ============================ epilogue ======================================

__global__ void pred_kernel(const float* __restrict__ allemb,
                            const int*   __restrict__ users,
                            const int*   __restrict__ bundles,
                            float*       __restrict__ out) {
    long long tid = (long long)blockIdx.x * blockDim.x + threadIdx.x;
    int pair = (int)(tid >> 4);
    int lane = (int)(tid & 15);
    if (pair >= BATCH * NUM_CAND) return;
    int b  = pair / NUM_CAND;
    int u  = users[b];
    int bd = bundles[pair];
    float4 uu = ((const float4*)(allemb + (size_t)u * EMB))[lane];
    float4 bb = ((const float4*)(allemb + (size_t)(NUM_USERS + bd) * EMB))[lane];
    float d = uu.x * bb.x + uu.y * bb.y + uu.z * bb.z + uu.w * bb.w;
    d += __shfl_xor(d, 8, 16);
    d += __shfl_xor(d, 4, 16);
    d += __shfl_xor(d, 2, 16);
    d += __shfl_xor(d, 1, 16);
    if (lane == 0) out[pair] = d;
}

__global__ void usb_kernel(const float* __restrict__ allemb,
                           const int*   __restrict__ users,
                           const float* __restrict__ user_bound,
                           const float* __restrict__ loss_acc,
                           float*       __restrict__ out) {
    long long tid = (long long)blockIdx.x * blockDim.x + threadIdx.x;
    int b    = (int)(tid >> 4);
    int lane = (int)(tid & 15);
    if (b >= BATCH) return;
    int u = users[b];
    float4 uu = ((const float4*)(allemb + (size_t)u * EMB))[lane];
    float4 w  = ((const float4*)user_bound)[lane];
    float d = uu.x * w.x + uu.y * w.y + uu.z * w.z + uu.w * w.w;
    d += __shfl_xor(d, 8, 16);
    d += __shfl_xor(d, 4, 16);
    d += __shfl_xor(d, 2, 16);
    d += __shfl_xor(d, 1, 16);
    if (lane == 0) out[BATCH * NUM_CAND + b] = d;
    if (tid == 0)  out[BATCH * NUM_CAND + BATCH] = EMBED_L2_NORM * loss_acc[0];
}

// ============================================================================

extern "C" void kernel_launch(void* const* d_in, const int* in_sizes, int n_in,
                              void* d_out, int out_size, void* d_ws, size_t ws_size,
                              hipStream_t stream) {
    const float* users_feat   = (const float*)d_in[0];
    const float* bundles_feat = (const float*)d_in[1];
    const float* user_bound   = (const float*)d_in[2];
    const float* graph_vals   = (const float*)d_in[3];
    const int*   graph_rows   = (const int*)d_in[4];
    const int*   graph_cols   = (const int*)d_in[5];
    const int*   users        = (const int*)d_in[6];
    const int*   bundles      = (const int*)d_in[7];
    float* out = (float*)d_out;

    float* allemb = (float*)d_ws;

    if (ws_size >= WS_NEEDED_BYTES) {
        // -------- sorted (gather) path --------
        int*   hist    = (int*)(allemb + ALLEMB_FLOATS);
        float* loss    = (float*)(hist + N_NODES);
        int*   offsets = (int*)(loss + 1);
        int*   cursor  = offsets + (N_NODES + 1);
        int2*  sorted  = (int2*)(cursor + N_NODES);

        // zero hist + loss in one shot (contiguous)
        hipMemsetAsync(hist, 0, (N_NODES + 1) * sizeof(int), stream);

        hist_kernel<<<(NNZ + 255) / 256, 256, 0, stream>>>(graph_rows, hist);
        scan_kernel<<<1, 1024, 0, stream>>>(hist, offsets, cursor);
        place_kernel<<<(NNZ + 255) / 256, 256, 0, stream>>>(graph_vals, graph_rows,
                                                            graph_cols, cursor, sorted);
        {
            long long threads = (long long)N_NODES * 16;
            int grid = (int)((threads + 255) / 256);
            gather_kernel<<<grid, 256, 0, stream>>>(users_feat, bundles_feat,
                                                    offsets, sorted, allemb, loss);
        }
        pred_kernel<<<(BATCH * NUM_CAND * 16 + 255) / 256, 256, 0, stream>>>(
            allemb, users, bundles, out);
        usb_kernel<<<(BATCH * 16 + 255) / 256, 256, 0, stream>>>(
            allemb, users, user_bound, loss, out);
    } else {
        // -------- fallback: atomic scatter path --------
        float* loss = allemb + ALLEMB_FLOATS;
        hipMemsetAsync(d_ws, 0, (ALLEMB_FLOATS + 1) * sizeof(float), stream);
        {
            long long threads = (long long)NNZ * 16;
            int grid = (int)((threads + 255) / 256);
            scatter_kernel<<<grid, 256, 0, stream>>>(users_feat, bundles_feat,
                                                     graph_vals, graph_rows,
                                                     graph_cols, allemb);
        }
        combine_kernel<<<2048, 256, 0, stream>>>(users_feat, bundles_feat, allemb, loss);
        pred_kernel<<<(BATCH * NUM_CAND * 16 + 255) / 256, 256, 0, stream>>>(
            allemb, users, bundles, out);
        usb_kernel<<<(BATCH * 16 + 255) / 256, 256, 0, stream>>>(
            allemb, users, user_bound, loss, out);
    }
}

// Round 3
// 925.524 us; speedup vs baseline: 2.8000x; 1.0034x over previous
//
#include <hip/hip_runtime.h>

#define NUM_USERS   100000
#define NUM_BUNDLES 50000
#define N_NODES     150000
#define EMB         64
#define NNZ         3000000
#define BATCH       2048
#define NUM_CAND    100
#define EMBED_L2_NORM 0.0001f

// ---------------------------------------------------------------------------
// ws layout (sorted path):
//   float allemb[N_NODES*EMB]      9,600,000 f32   (38.4 MB)
//   int   hist[N_NODES]              150,000
//   float loss[1]                          1       (memset together with hist)
//   int   offsets[N_NODES+1]         150,001
//   int   cursor[N_NODES]            150,000
//   int2  sorted[NNZ]              3,000,000 int2  (24 MB, 8B-aligned)
// ---------------------------------------------------------------------------
#define ALLEMB_FLOATS ((size_t)N_NODES * EMB)
#define WS_NEEDED_BYTES ((ALLEMB_FLOATS + 150000 + 1 + 150001 + 150000) * 4 + (size_t)NNZ * 8)

__device__ __forceinline__ const float4* emb_row(const float* uf, const float* bf, int col) {
    return (col < NUM_USERS) ? (const float4*)(uf + (size_t)col * EMB)
                             : (const float4*)(bf + (size_t)(col - NUM_USERS) * EMB);
}

// ============================ sorted path ==================================

__global__ void hist_kernel(const int* __restrict__ rows, int* __restrict__ hist) {
    int e = blockIdx.x * blockDim.x + threadIdx.x;
    if (e >= NNZ) return;
    atomicAdd(&hist[rows[e]], 1);
}

// single-block scan: 1024 threads, 4 elems/thread, 37 chunks
__global__ void scan_kernel(const int* __restrict__ hist,
                            int* __restrict__ offsets,
                            int* __restrict__ cursor) {
    __shared__ int wave_tot[16];
    __shared__ int wave_pref[16];
    __shared__ int s_chunk_total;
    __shared__ int s_carry;
    if (threadIdx.x == 0) s_carry = 0;
    __syncthreads();
    const int lane = threadIdx.x & 63;
    const int wid  = threadIdx.x >> 6;
    for (int base = 0; base < N_NODES; base += 1024 * 4) {
        int idx = base + threadIdx.x * 4;
        int v0 = 0, v1 = 0, v2 = 0, v3 = 0;
        if (idx + 3 < N_NODES) {
            int4 h = *(const int4*)(hist + idx);
            v0 = h.x; v1 = h.y; v2 = h.z; v3 = h.w;
        } else {
            if (idx + 0 < N_NODES) v0 = hist[idx + 0];
            if (idx + 1 < N_NODES) v1 = hist[idx + 1];
            if (idx + 2 < N_NODES) v2 = hist[idx + 2];
        }
        int tsum = v0 + v1 + v2 + v3;
        int x = tsum;
        #pragma unroll
        for (int off = 1; off < 64; off <<= 1) {
            int t = __shfl_up(x, off);
            if (lane >= off) x += t;
        }
        if (lane == 63) wave_tot[wid] = x;
        __syncthreads();
        if (wid == 0 && lane < 16) {
            int w = wave_tot[lane];
            int y = w;
            #pragma unroll
            for (int off = 1; off < 16; off <<= 1) {
                int t = __shfl_up(y, off);
                if (lane >= off) y += t;
            }
            wave_pref[lane] = y - w;
            if (lane == 15) s_chunk_total = y;
        }
        __syncthreads();
        int excl = s_carry + wave_pref[wid] + (x - tsum);
        if (idx < N_NODES)     { offsets[idx]     = excl; cursor[idx]     = excl; }
        excl += v0;
        if (idx + 1 < N_NODES) { offsets[idx + 1] = excl; cursor[idx + 1] = excl; }
        excl += v1;
        if (idx + 2 < N_NODES) { offsets[idx + 2] = excl; cursor[idx + 2] = excl; }
        excl += v2;
        if (idx + 3 < N_NODES) { offsets[idx + 3] = excl; cursor[idx + 3] = excl; }
        __syncthreads();
        if (threadIdx.x == 0) s_carry += s_chunk_total;
        __syncthreads();
    }
    if (threadIdx.x == 0) offsets[N_NODES] = s_carry;
}

__global__ void place_kernel(const float* __restrict__ vals,
                             const int*   __restrict__ rows,
                             const int*   __restrict__ cols,
                             int* __restrict__ cursor,
                             int2* __restrict__ sorted) {
    int e = blockIdx.x * blockDim.x + threadIdx.x;
    if (e >= NNZ) return;
    int row = rows[e];
    int pos = atomicAdd(&cursor[row], 1);
    int2 p;
    p.x = __float_as_int(vals[e]);
    p.y = cols[e];
    sorted[pos] = p;
}

// 16 lanes per row, edge loop unrolled x4 for memory-level parallelism
__global__ void gather_kernel(const float* __restrict__ users_feat,
                              const float* __restrict__ bundles_feat,
                              const int*   __restrict__ offsets,
                              const int2*  __restrict__ sorted,
                              float* __restrict__ allemb,
                              float* __restrict__ loss_acc) {
    int tid  = blockIdx.x * blockDim.x + threadIdx.x;
    int row  = tid >> 4;
    int lane = tid & 15;
    bool valid = row < N_NODES;
    float4 acc0 = {0.f, 0.f, 0.f, 0.f};
    float4 acc1 = {0.f, 0.f, 0.f, 0.f};
    if (valid) {
        int beg = offsets[row], end = offsets[row + 1];
        int e = beg;
        for (; e + 4 <= end; e += 4) {
            int2 p0 = sorted[e + 0];
            int2 p1 = sorted[e + 1];
            int2 p2 = sorted[e + 2];
            int2 p3 = sorted[e + 3];
            float4 x0 = emb_row(users_feat, bundles_feat, p0.y)[lane];
            float4 x1 = emb_row(users_feat, bundles_feat, p1.y)[lane];
            float4 x2 = emb_row(users_feat, bundles_feat, p2.y)[lane];
            float4 x3 = emb_row(users_feat, bundles_feat, p3.y)[lane];
            float v0 = __int_as_float(p0.x);
            float v1 = __int_as_float(p1.x);
            float v2 = __int_as_float(p2.x);
            float v3 = __int_as_float(p3.x);
            acc0.x += v0 * x0.x; acc0.y += v0 * x0.y; acc0.z += v0 * x0.z; acc0.w += v0 * x0.w;
            acc1.x += v1 * x1.x; acc1.y += v1 * x1.y; acc1.z += v1 * x1.z; acc1.w += v1 * x1.w;
            acc0.x += v2 * x2.x; acc0.y += v2 * x2.y; acc0.z += v2 * x2.z; acc0.w += v2 * x2.w;
            acc1.x += v3 * x3.x; acc1.y += v3 * x3.y; acc1.z += v3 * x3.z; acc1.w += v3 * x3.w;
        }
        for (; e < end; ++e) {
            int2 p = sorted[e];
            float v = __int_as_float(p.x);
            float4 x = emb_row(users_feat, bundles_feat, p.y)[lane];
            acc0.x += v * x.x; acc0.y += v * x.y; acc0.z += v * x.z; acc0.w += v * x.w;
        }
        float4 e0 = emb_row(users_feat, bundles_feat, row)[lane];
        acc0.x = 0.5f * (e0.x + acc0.x + acc1.x);
        acc0.y = 0.5f * (e0.y + acc0.y + acc1.y);
        acc0.z = 0.5f * (e0.z + acc0.z + acc1.z);
        acc0.w = 0.5f * (e0.w + acc0.w + acc1.w);
        ((float4*)(allemb + (size_t)row * EMB))[lane] = acc0;
    }
    float sq = valid ? (acc0.x * acc0.x + acc0.y * acc0.y + acc0.z * acc0.z + acc0.w * acc0.w) : 0.f;
    #pragma unroll
    for (int off = 32; off > 0; off >>= 1) sq += __shfl_xor(sq, off);
    if ((threadIdx.x & 63) == 0) atomicAdd(loss_acc, sq);
}

// ============================ fallback path =================================

__global__ void scatter_kernel(const float* __restrict__ users_feat,
                               const float* __restrict__ bundles_feat,
                               const float* __restrict__ vals,
                               const int*   __restrict__ rows,
                               const int*   __restrict__ cols,
                               float*       __restrict__ acc) {
    long long tid = (long long)blockIdx.x * blockDim.x + threadIdx.x;
    int e    = (int)(tid >> 4);
    int lane = (int)(tid & 15);
    if (e >= NNZ) return;
    int   row = rows[e];
    int   col = cols[e];
    float v   = vals[e];
    float4 x = emb_row(users_feat, bundles_feat, col)[lane];
    float* dst = acc + (size_t)row * EMB + lane * 4;
    atomicAdd(dst + 0, v * x.x);
    atomicAdd(dst + 1, v * x.y);
    atomicAdd(dst + 2, v * x.z);
    atomicAdd(dst + 3, v * x.w);
}

__global__ void combine_kernel(const float* __restrict__ users_feat,
                               const float* __restrict__ bundles_feat,
                               float*       __restrict__ acc,
                               float*       __restrict__ loss_acc) {
    const int TOTAL4 = N_NODES * (EMB / 4);
    const int U4     = NUM_USERS * (EMB / 4);
    float lsum = 0.f;
    for (int i = blockIdx.x * blockDim.x + threadIdx.x; i < TOTAL4;
         i += gridDim.x * blockDim.x) {
        float4 a = (i < U4) ? ((const float4*)users_feat)[i]
                            : ((const float4*)bundles_feat)[i - U4];
        float4* pa = (float4*)acc + i;
        float4 b = *pa;
        float4 r;
        r.x = 0.5f * (a.x + b.x);
        r.y = 0.5f * (a.y + b.y);
        r.z = 0.5f * (a.z + b.z);
        r.w = 0.5f * (a.w + b.w);
        *pa = r;
        lsum += r.x * r.x + r.y * r.y + r.z * r.z + r.w * r.w;
    }
    #pragma unroll
    for (int off = 32; off > 0; off >>= 1) lsum += __shfl_down(lsum, off);
    __shared__ float ws_[4];
    int wid = threadIdx.x >> 6;
    if ((threadIdx.x & 63) == 0) ws_[wid] = lsum;
    __syncthreads();
    if (threadIdx.x == 0) atomicAdd(loss_acc, ws_[0] + ws_[1] + ws_[2] + ws_[3]);
}

// ============================ epilogue ======================================

__global__ void pred_kernel(const float* __restrict__ allemb,
                            const int*   __restrict__ users,
                            const int*   __restrict__ bundles,
                            float*       __restrict__ out) {
    long long tid = (long long)blockIdx.x * blockDim.x + threadIdx.x;
    int pair = (int)(tid >> 4);
    int lane = (int)(tid & 15);
    if (pair >= BATCH * NUM_CAND) return;
    int b  = pair / NUM_CAND;
    int u  = users[b];
    int bd = bundles[pair];
    float4 uu = ((const float4*)(allemb + (size_t)u * EMB))[lane];
    float4 bb = ((const float4*)(allemb + (size_t)(NUM_USERS + bd) * EMB))[lane];
    float d = uu.x * bb.x + uu.y * bb.y + uu.z * bb.z + uu.w * bb.w;
    d += __shfl_xor(d, 8, 16);
    d += __shfl_xor(d, 4, 16);
    d += __shfl_xor(d, 2, 16);
    d += __shfl_xor(d, 1, 16);
    if (lane == 0) out[pair] = d;
}

__global__ void usb_kernel(const float* __restrict__ allemb,
                           const int*   __restrict__ users,
                           const float* __restrict__ user_bound,
                           const float* __restrict__ loss_acc,
                           float*       __restrict__ out) {
    long long tid = (long long)blockIdx.x * blockDim.x + threadIdx.x;
    int b    = (int)(tid >> 4);
    int lane = (int)(tid & 15);
    if (b >= BATCH) return;
    int u = users[b];
    float4 uu = ((const float4*)(allemb + (size_t)u * EMB))[lane];
    float4 w  = ((const float4*)user_bound)[lane];
    float d = uu.x * w.x + uu.y * w.y + uu.z * w.z + uu.w * w.w;
    d += __shfl_xor(d, 8, 16);
    d += __shfl_xor(d, 4, 16);
    d += __shfl_xor(d, 2, 16);
    d += __shfl_xor(d, 1, 16);
    if (lane == 0) out[BATCH * NUM_CAND + b] = d;
    if (tid == 0)  out[BATCH * NUM_CAND + BATCH] = EMBED_L2_NORM * loss_acc[0];
}

// ============================================================================

extern "C" void kernel_launch(void* const* d_in, const int* in_sizes, int n_in,
                              void* d_out, int out_size, void* d_ws, size_t ws_size,
                              hipStream_t stream) {
    const float* users_feat   = (const float*)d_in[0];
    const float* bundles_feat = (const float*)d_in[1];
    const float* user_bound   = (const float*)d_in[2];
    const float* graph_vals   = (const float*)d_in[3];
    const int*   graph_rows   = (const int*)d_in[4];
    const int*   graph_cols   = (const int*)d_in[5];
    const int*   users        = (const int*)d_in[6];
    const int*   bundles      = (const int*)d_in[7];
    float* out = (float*)d_out;

    float* allemb = (float*)d_ws;

    if (ws_size >= WS_NEEDED_BYTES) {
        // -------- sorted (gather) path --------
        int*   hist    = (int*)(allemb + ALLEMB_FLOATS);
        float* loss    = (float*)(hist + N_NODES);
        int*   offsets = (int*)(loss + 1);
        int*   cursor  = offsets + (N_NODES + 1);
        int2*  sorted  = (int2*)(cursor + N_NODES);

        hipMemsetAsync(hist, 0, (N_NODES + 1) * sizeof(int), stream);

        hist_kernel<<<(NNZ + 255) / 256, 256, 0, stream>>>(graph_rows, hist);
        scan_kernel<<<1, 1024, 0, stream>>>(hist, offsets, cursor);
        place_kernel<<<(NNZ + 255) / 256, 256, 0, stream>>>(graph_vals, graph_rows,
                                                            graph_cols, cursor, sorted);
        {
            long long threads = (long long)N_NODES * 16;
            int grid = (int)((threads + 255) / 256);
            gather_kernel<<<grid, 256, 0, stream>>>(users_feat, bundles_feat,
                                                    offsets, sorted, allemb, loss);
        }
        pred_kernel<<<(BATCH * NUM_CAND * 16 + 255) / 256, 256, 0, stream>>>(
            allemb, users, bundles, out);
        usb_kernel<<<(BATCH * 16 + 255) / 256, 256, 0, stream>>>(
            allemb, users, user_bound, loss, out);
    } else {
        // -------- fallback: atomic scatter path --------
        float* loss = allemb + ALLEMB_FLOATS;
        hipMemsetAsync(d_ws, 0, (ALLEMB_FLOATS + 1) * sizeof(float), stream);
        {
            long long threads = (long long)NNZ * 16;
            int grid = (int)((threads + 255) / 256);
            scatter_kernel<<<grid, 256, 0, stream>>>(users_feat, bundles_feat,
                                                     graph_vals, graph_rows,
                                                     graph_cols, allemb);
        }
        combine_kernel<<<2048, 256, 0, stream>>>(users_feat, bundles_feat, allemb, loss);
        pred_kernel<<<(BATCH * NUM_CAND * 16 + 255) / 256, 256, 0, stream>>>(
            allemb, users, bundles, out);
        usb_kernel<<<(BATCH * 16 + 255) / 256, 256, 0, stream>>>(
            allemb, users, user_bound, loss, out);
    }
}

// Round 4
// 692.161 us; speedup vs baseline: 3.7440x; 1.3372x over previous
//
#include <hip/hip_runtime.h>

#define NUM_USERS   100000
#define NUM_BUNDLES 50000
#define N_NODES     150000
#define EMB         64
#define NNZ         3000000
#define BATCH       2048
#define NUM_CAND    100
#define EMBED_L2_NORM 0.0001f

// ---------------------------------------------------------------------------
// ws layout (sorted bf16 path), all sizes in bytes:
//   ebf   [N_NODES*64 bf16]   19,200,000   (embed_0 in bf16, row-major 128 B/row)
//   aeb   [N_NODES*64 bf16]   19,200,000   (all_embeds in bf16)
//   sorted[NNZ int2]          24,000,000
//   hist  [N_NODES int]          600,000
//   loss  [1 float]                    4
//   offsets[N_NODES+1 int]       600,004
//   cursor[N_NODES int]          600,000
// total = 64,200,008  (identical to previous round's need: 2x bf16 == 1x f32)
// ---------------------------------------------------------------------------
#define EBF_BYTES   ((size_t)N_NODES * EMB * 2)
#define SORT_BYTES  ((size_t)NNZ * 8)
#define WS_NEEDED_BYTES (2 * EBF_BYTES + SORT_BYTES + ((size_t)N_NODES * 3 + 2) * 4)

// ============================ bf16 helpers =================================

__device__ __forceinline__ float bflo(unsigned int u) {
    union { unsigned int i; float f; } v; v.i = u << 16; return v.f;
}
__device__ __forceinline__ float bfhi(unsigned int u) {
    union { unsigned int i; float f; } v; v.i = u & 0xffff0000u; return v.f;
}
__device__ __forceinline__ unsigned int f2bf(float f) {   // RTNE
    union { float f; unsigned int i; } v; v.f = f;
    return (v.i + 0x7fffu + ((v.i >> 16) & 1u)) >> 16;
}
__device__ __forceinline__ void fma8(float v, uint4 q, float a[8]) {
    a[0] += v * bflo(q.x); a[1] += v * bfhi(q.x);
    a[2] += v * bflo(q.y); a[3] += v * bfhi(q.y);
    a[4] += v * bflo(q.z); a[5] += v * bfhi(q.z);
    a[6] += v * bflo(q.w); a[7] += v * bfhi(q.w);
}
__device__ __forceinline__ void unp8(uint4 q, float o[8]) {
    o[0] = bflo(q.x); o[1] = bfhi(q.x); o[2] = bflo(q.y); o[3] = bfhi(q.y);
    o[4] = bflo(q.z); o[5] = bfhi(q.z); o[6] = bflo(q.w); o[7] = bfhi(q.w);
}

__device__ __forceinline__ const float4* emb_row(const float* uf, const float* bf, int col) {
    return (col < NUM_USERS) ? (const float4*)(uf + (size_t)col * EMB)
                             : (const float4*)(bf + (size_t)(col - NUM_USERS) * EMB);
}

// ============================ sorted bf16 path =============================

// embed_0 (f32) -> ebf (bf16), 2.4M float4 -> uint2
__global__ void convert_kernel(const float4* __restrict__ uf4,
                               const float4* __restrict__ bf4,
                               uint2* __restrict__ ebf2) {
    const int TOTAL4 = N_NODES * (EMB / 4);
    const int U4     = NUM_USERS * (EMB / 4);
    for (int i = blockIdx.x * blockDim.x + threadIdx.x; i < TOTAL4;
         i += gridDim.x * blockDim.x) {
        float4 a = (i < U4) ? uf4[i] : bf4[i - U4];
        uint2 o;
        o.x = f2bf(a.x) | (f2bf(a.y) << 16);
        o.y = f2bf(a.z) | (f2bf(a.w) << 16);
        ebf2[i] = o;
    }
}

__global__ void hist_kernel(const int4* __restrict__ rows4, int* __restrict__ hist) {
    int i = blockIdx.x * blockDim.x + threadIdx.x;
    if (i >= NNZ / 4) return;
    int4 r = rows4[i];
    atomicAdd(&hist[r.x], 1);
    atomicAdd(&hist[r.y], 1);
    atomicAdd(&hist[r.z], 1);
    atomicAdd(&hist[r.w], 1);
}

// single-block scan: 1024 threads, 4 elems/thread, 37 chunks
__global__ void scan_kernel(const int* __restrict__ hist,
                            int* __restrict__ offsets,
                            int* __restrict__ cursor) {
    __shared__ int wave_tot[16];
    __shared__ int wave_pref[16];
    __shared__ int s_chunk_total;
    __shared__ int s_carry;
    if (threadIdx.x == 0) s_carry = 0;
    __syncthreads();
    const int lane = threadIdx.x & 63;
    const int wid  = threadIdx.x >> 6;
    for (int base = 0; base < N_NODES; base += 1024 * 4) {
        int idx = base + threadIdx.x * 4;
        int v0 = 0, v1 = 0, v2 = 0, v3 = 0;
        if (idx + 3 < N_NODES) {
            int4 h = *(const int4*)(hist + idx);
            v0 = h.x; v1 = h.y; v2 = h.z; v3 = h.w;
        } else {
            if (idx + 0 < N_NODES) v0 = hist[idx + 0];
            if (idx + 1 < N_NODES) v1 = hist[idx + 1];
            if (idx + 2 < N_NODES) v2 = hist[idx + 2];
        }
        int tsum = v0 + v1 + v2 + v3;
        int x = tsum;
        #pragma unroll
        for (int off = 1; off < 64; off <<= 1) {
            int t = __shfl_up(x, off);
            if (lane >= off) x += t;
        }
        if (lane == 63) wave_tot[wid] = x;
        __syncthreads();
        if (wid == 0 && lane < 16) {
            int w = wave_tot[lane];
            int y = w;
            #pragma unroll
            for (int off = 1; off < 16; off <<= 1) {
                int t = __shfl_up(y, off);
                if (lane >= off) y += t;
            }
            wave_pref[lane] = y - w;
            if (lane == 15) s_chunk_total = y;
        }
        __syncthreads();
        int excl = s_carry + wave_pref[wid] + (x - tsum);
        if (idx < N_NODES)     { offsets[idx]     = excl; cursor[idx]     = excl; }
        excl += v0;
        if (idx + 1 < N_NODES) { offsets[idx + 1] = excl; cursor[idx + 1] = excl; }
        excl += v1;
        if (idx + 2 < N_NODES) { offsets[idx + 2] = excl; cursor[idx + 2] = excl; }
        excl += v2;
        if (idx + 3 < N_NODES) { offsets[idx + 3] = excl; cursor[idx + 3] = excl; }
        __syncthreads();
        if (threadIdx.x == 0) s_carry += s_chunk_total;
        __syncthreads();
    }
    if (threadIdx.x == 0) offsets[N_NODES] = s_carry;
}

__global__ void place_kernel(const float4* __restrict__ vals4,
                             const int4*   __restrict__ rows4,
                             const int4*   __restrict__ cols4,
                             int* __restrict__ cursor,
                             int2* __restrict__ sorted) {
    int i = blockIdx.x * blockDim.x + threadIdx.x;
    if (i >= NNZ / 4) return;
    int4   r = rows4[i];
    int4   c = cols4[i];
    float4 v = vals4[i];
    int p;
    p = atomicAdd(&cursor[r.x], 1); sorted[p] = make_int2(__float_as_int(v.x), c.x);
    p = atomicAdd(&cursor[r.y], 1); sorted[p] = make_int2(__float_as_int(v.y), c.y);
    p = atomicAdd(&cursor[r.z], 1); sorted[p] = make_int2(__float_as_int(v.z), c.z);
    p = atomicAdd(&cursor[r.w], 1); sorted[p] = make_int2(__float_as_int(v.w), c.w);
}

// 8 lanes per row: each lane covers 8 consecutive bf16 (one uint4 = full row slice)
__global__ void gather_bf_kernel(const uint4* __restrict__ ebf,
                                 const int*   __restrict__ offsets,
                                 const int2*  __restrict__ sorted,
                                 uint4* __restrict__ aeb,
                                 float* __restrict__ loss_acc) {
    int tid  = blockIdx.x * blockDim.x + threadIdx.x;
    int row  = tid >> 3;
    int lane = tid & 7;
    bool valid = row < N_NODES;
    float a[8], b[8];
    #pragma unroll
    for (int i = 0; i < 8; i++) { a[i] = 0.f; b[i] = 0.f; }
    if (valid) {
        int beg = offsets[row], end = offsets[row + 1];
        int e = beg;
        for (; e + 4 <= end; e += 4) {
            int2 p0 = sorted[e + 0];
            int2 p1 = sorted[e + 1];
            int2 p2 = sorted[e + 2];
            int2 p3 = sorted[e + 3];
            uint4 q0 = ebf[(size_t)p0.y * 8 + lane];
            uint4 q1 = ebf[(size_t)p1.y * 8 + lane];
            uint4 q2 = ebf[(size_t)p2.y * 8 + lane];
            uint4 q3 = ebf[(size_t)p3.y * 8 + lane];
            fma8(__int_as_float(p0.x), q0, a);
            fma8(__int_as_float(p1.x), q1, b);
            fma8(__int_as_float(p2.x), q2, a);
            fma8(__int_as_float(p3.x), q3, b);
        }
        for (; e < end; ++e) {
            int2 p = sorted[e];
            uint4 q = ebf[(size_t)p.y * 8 + lane];
            fma8(__int_as_float(p.x), q, a);
        }
        uint4 qs = ebf[(size_t)row * 8 + lane];
        float e0[8];
        unp8(qs, e0);
        #pragma unroll
        for (int i = 0; i < 8; i++) a[i] = 0.5f * (e0[i] + a[i] + b[i]);
        uint4 o;
        o.x = f2bf(a[0]) | (f2bf(a[1]) << 16);
        o.y = f2bf(a[2]) | (f2bf(a[3]) << 16);
        o.z = f2bf(a[4]) | (f2bf(a[5]) << 16);
        o.w = f2bf(a[6]) | (f2bf(a[7]) << 16);
        aeb[(size_t)row * 8 + lane] = o;
    }
    float sq = 0.f;
    if (valid) {
        #pragma unroll
        for (int i = 0; i < 8; i++) sq += a[i] * a[i];
    }
    #pragma unroll
    for (int off = 32; off > 0; off >>= 1) sq += __shfl_xor(sq, off);
    if ((threadIdx.x & 63) == 0) atomicAdd(loss_acc, sq);
}

__global__ void pred_bf_kernel(const uint4* __restrict__ aeb,
                               const int*   __restrict__ users,
                               const int*   __restrict__ bundles,
                               float*       __restrict__ out) {
    int tid  = blockIdx.x * blockDim.x + threadIdx.x;
    int pair = tid >> 3;
    int lane = tid & 7;
    if (pair >= BATCH * NUM_CAND) return;
    int b  = pair / NUM_CAND;
    int u  = users[b];
    int bd = bundles[pair];
    uint4 qu = aeb[(size_t)u * 8 + lane];
    uint4 qb = aeb[(size_t)(NUM_USERS + bd) * 8 + lane];
    float d = bflo(qu.x) * bflo(qb.x) + bfhi(qu.x) * bfhi(qb.x)
            + bflo(qu.y) * bflo(qb.y) + bfhi(qu.y) * bfhi(qb.y)
            + bflo(qu.z) * bflo(qb.z) + bfhi(qu.z) * bfhi(qb.z)
            + bflo(qu.w) * bflo(qb.w) + bfhi(qu.w) * bfhi(qb.w);
    d += __shfl_xor(d, 4);
    d += __shfl_xor(d, 2);
    d += __shfl_xor(d, 1);
    if (lane == 0) out[pair] = d;
}

__global__ void usb_bf_kernel(const uint4* __restrict__ aeb,
                              const int*   __restrict__ users,
                              const float* __restrict__ user_bound,
                              const float* __restrict__ loss_acc,
                              float*       __restrict__ out) {
    int tid  = blockIdx.x * blockDim.x + threadIdx.x;
    int b    = tid >> 3;
    int lane = tid & 7;
    if (b >= BATCH) return;
    int u = users[b];
    uint4 qu = aeb[(size_t)u * 8 + lane];
    const float4* w4 = (const float4*)user_bound;
    float4 w0 = w4[lane * 2], w1 = w4[lane * 2 + 1];
    float d = bflo(qu.x) * w0.x + bfhi(qu.x) * w0.y
            + bflo(qu.y) * w0.z + bfhi(qu.y) * w0.w
            + bflo(qu.z) * w1.x + bfhi(qu.z) * w1.y
            + bflo(qu.w) * w1.z + bfhi(qu.w) * w1.w;
    d += __shfl_xor(d, 4);
    d += __shfl_xor(d, 2);
    d += __shfl_xor(d, 1);
    if (lane == 0) out[BATCH * NUM_CAND + b] = d;
    if (tid == 0)  out[BATCH * NUM_CAND + BATCH] = EMBED_L2_NORM * loss_acc[0];
}

// ============================ fallback path (f32 atomic) ====================

__global__ void scatter_kernel(const float* __restrict__ users_feat,
                               const float* __restrict__ bundles_feat,
                               const float* __restrict__ vals,
                               const int*   __restrict__ rows,
                               const int*   __restrict__ cols,
                               float*       __restrict__ acc) {
    long long tid = (long long)blockIdx.x * blockDim.x + threadIdx.x;
    int e    = (int)(tid >> 4);
    int lane = (int)(tid & 15);
    if (e >= NNZ) return;
    int   row = rows[e];
    int   col = cols[e];
    float v   = vals[e];
    float4 x = emb_row(users_feat, bundles_feat, col)[lane];
    float* dst = acc + (size_t)row * EMB + lane * 4;
    atomicAdd(dst + 0, v * x.x);
    atomicAdd(dst + 1, v * x.y);
    atomicAdd(dst + 2, v * x.z);
    atomicAdd(dst + 3, v * x.w);
}

__global__ void combine_kernel(const float* __restrict__ users_feat,
                               const float* __restrict__ bundles_feat,
                               float*       __restrict__ acc,
                               float*       __restrict__ loss_acc) {
    const int TOTAL4 = N_NODES * (EMB / 4);
    const int U4     = NUM_USERS * (EMB / 4);
    float lsum = 0.f;
    for (int i = blockIdx.x * blockDim.x + threadIdx.x; i < TOTAL4;
         i += gridDim.x * blockDim.x) {
        float4 a = (i < U4) ? ((const float4*)users_feat)[i]
                            : ((const float4*)bundles_feat)[i - U4];
        float4* pa = (float4*)acc + i;
        float4 bb = *pa;
        float4 r;
        r.x = 0.5f * (a.x + bb.x);
        r.y = 0.5f * (a.y + bb.y);
        r.z = 0.5f * (a.z + bb.z);
        r.w = 0.5f * (a.w + bb.w);
        *pa = r;
        lsum += r.x * r.x + r.y * r.y + r.z * r.z + r.w * r.w;
    }
    #pragma unroll
    for (int off = 32; off > 0; off >>= 1) lsum += __shfl_down(lsum, off);
    __shared__ float ws_[4];
    int wid = threadIdx.x >> 6;
    if ((threadIdx.x & 63) == 0) ws_[wid] = lsum;
    __syncthreads();
    if (threadIdx.x == 0) atomicAdd(loss_acc, ws_[0] + ws_[1] + ws_[2] + ws_[3]);
}

__global__ void pred_kernel(const float* __restrict__ allemb,
                            const int*   __restrict__ users,
                            const int*   __restrict__ bundles,
                            float*       __restrict__ out) {
    long long tid = (long long)blockIdx.x * blockDim.x + threadIdx.x;
    int pair = (int)(tid >> 4);
    int lane = (int)(tid & 15);
    if (pair >= BATCH * NUM_CAND) return;
    int b  = pair / NUM_CAND;
    int u  = users[b];
    int bd = bundles[pair];
    float4 uu = ((const float4*)(allemb + (size_t)u * EMB))[lane];
    float4 bb = ((const float4*)(allemb + (size_t)(NUM_USERS + bd) * EMB))[lane];
    float d = uu.x * bb.x + uu.y * bb.y + uu.z * bb.z + uu.w * bb.w;
    d += __shfl_xor(d, 8, 16);
    d += __shfl_xor(d, 4, 16);
    d += __shfl_xor(d, 2, 16);
    d += __shfl_xor(d, 1, 16);
    if (lane == 0) out[pair] = d;
}

__global__ void usb_kernel(const float* __restrict__ allemb,
                           const int*   __restrict__ users,
                           const float* __restrict__ user_bound,
                           const float* __restrict__ loss_acc,
                           float*       __restrict__ out) {
    long long tid = (long long)blockIdx.x * blockDim.x + threadIdx.x;
    int b    = (int)(tid >> 4);
    int lane = (int)(tid & 15);
    if (b >= BATCH) return;
    int u = users[b];
    float4 uu = ((const float4*)(allemb + (size_t)u * EMB))[lane];
    float4 w  = ((const float4*)user_bound)[lane];
    float d = uu.x * w.x + uu.y * w.y + uu.z * w.z + uu.w * w.w;
    d += __shfl_xor(d, 8, 16);
    d += __shfl_xor(d, 4, 16);
    d += __shfl_xor(d, 2, 16);
    d += __shfl_xor(d, 1, 16);
    if (lane == 0) out[BATCH * NUM_CAND + b] = d;
    if (tid == 0)  out[BATCH * NUM_CAND + BATCH] = EMBED_L2_NORM * loss_acc[0];
}

// ============================================================================

extern "C" void kernel_launch(void* const* d_in, const int* in_sizes, int n_in,
                              void* d_out, int out_size, void* d_ws, size_t ws_size,
                              hipStream_t stream) {
    const float* users_feat   = (const float*)d_in[0];
    const float* bundles_feat = (const float*)d_in[1];
    const float* user_bound   = (const float*)d_in[2];
    const float* graph_vals   = (const float*)d_in[3];
    const int*   graph_rows   = (const int*)d_in[4];
    const int*   graph_cols   = (const int*)d_in[5];
    const int*   users        = (const int*)d_in[6];
    const int*   bundles      = (const int*)d_in[7];
    float* out = (float*)d_out;

    if (ws_size >= WS_NEEDED_BYTES) {
        // -------- sorted bf16 gather path --------
        char*  base    = (char*)d_ws;
        uint4* ebf     = (uint4*)base;
        uint4* aeb     = (uint4*)(base + EBF_BYTES);
        int2*  sorted  = (int2*)(base + 2 * EBF_BYTES);
        int*   hist    = (int*)(base + 2 * EBF_BYTES + SORT_BYTES);
        float* loss    = (float*)(hist + N_NODES);
        int*   offsets = (int*)(loss + 1);
        int*   cursor  = offsets + (N_NODES + 1);

        hipMemsetAsync(hist, 0, (N_NODES + 1) * sizeof(int), stream);

        convert_kernel<<<2048, 256, 0, stream>>>((const float4*)users_feat,
                                                 (const float4*)bundles_feat,
                                                 (uint2*)ebf);
        hist_kernel<<<(NNZ / 4 + 255) / 256, 256, 0, stream>>>(
            (const int4*)graph_rows, hist);
        scan_kernel<<<1, 1024, 0, stream>>>(hist, offsets, cursor);
        place_kernel<<<(NNZ / 4 + 255) / 256, 256, 0, stream>>>(
            (const float4*)graph_vals, (const int4*)graph_rows,
            (const int4*)graph_cols, cursor, sorted);
        {
            long long threads = (long long)N_NODES * 8;
            int grid = (int)((threads + 255) / 256);
            gather_bf_kernel<<<grid, 256, 0, stream>>>(ebf, offsets, sorted, aeb, loss);
        }
        pred_bf_kernel<<<(BATCH * NUM_CAND * 8 + 255) / 256, 256, 0, stream>>>(
            aeb, users, bundles, out);
        usb_bf_kernel<<<(BATCH * 8 + 255) / 256, 256, 0, stream>>>(
            aeb, users, user_bound, loss, out);
    } else {
        // -------- fallback: atomic scatter path (f32) --------
        float* allemb = (float*)d_ws;
        float* loss   = allemb + (size_t)N_NODES * EMB;
        hipMemsetAsync(d_ws, 0, ((size_t)N_NODES * EMB + 1) * sizeof(float), stream);
        {
            long long threads = (long long)NNZ * 16;
            int grid = (int)((threads + 255) / 256);
            scatter_kernel<<<grid, 256, 0, stream>>>(users_feat, bundles_feat,
                                                     graph_vals, graph_rows,
                                                     graph_cols, allemb);
        }
        combine_kernel<<<2048, 256, 0, stream>>>(users_feat, bundles_feat, allemb, loss);
        pred_kernel<<<(BATCH * NUM_CAND * 16 + 255) / 256, 256, 0, stream>>>(
            allemb, users, bundles, out);
        usb_kernel<<<(BATCH * 16 + 255) / 256, 256, 0, stream>>>(
            allemb, users, user_bound, loss, out);
    }
}